// Round 5
// baseline (224.396 us; speedup 1.0000x reference)
//
#include <hip/hip_runtime.h>

typedef short  s8v   __attribute__((ext_vector_type(8)));
typedef float  f32x4 __attribute__((ext_vector_type(4)));

#define SEQ 2048
#define WID 768

__device__ __forceinline__ unsigned fbits(float f) {
    union { float f; unsigned u; } v; v.f = f; return v.u;
}
__device__ __forceinline__ float bitsf(unsigned u) {
    union { unsigned u; float f; } v; v.u = u; return v.f;
}
__device__ __forceinline__ unsigned short f2b(float f) {
    unsigned u = fbits(f);
    return (unsigned short)((u + 0x7FFFu + ((u >> 16) & 1u)) >> 16);   // RNE
}
__device__ __forceinline__ unsigned packRNE(float a, float b) {
    unsigned ta = fbits(a) + 0x7FFFu + ((fbits(a) >> 16) & 1u);
    unsigned tb = fbits(b) + 0x7FFFu + ((fbits(b) >> 16) & 1u);
    return __builtin_amdgcn_perm(tb, ta, 0x07060302u);
}
__device__ __forceinline__ unsigned packTRUNC(float a, float b) {
    return __builtin_amdgcn_perm(fbits(b), fbits(a), 0x07060302u);
}
__device__ __forceinline__ f32x4 zero4() { f32x4 z = {0.f, 0.f, 0.f, 0.f}; return z; }

// ---------------------------------------------------------------------------
// prep (verbatim, verified): PM mask-bit packing + W transpose to bf16.
// ---------------------------------------------------------------------------
__global__ __launch_bounds__(256) void prep_kernel(
    const int* __restrict__ mask,
    const float* __restrict__ Wq, const float* __restrict__ Wk, const float* __restrict__ Wv,
    unsigned* __restrict__ PM, unsigned short* __restrict__ Wt)
{
    const int tid = threadIdx.x;
    const int blk = blockIdx.x;
    if (blk < 512) {
        const int gid  = blk * 4 + (tid >> 6);
        const int lane = tid & 63, quad = lane >> 4, c = lane & 15;
        const int qb = gid >> 5, kb = gid & 31;
        unsigned w = 0;
        #pragma unroll
        for (int mt = 0; mt < 2; ++mt)
            #pragma unroll
            for (int i = 0; i < 4; ++i) {
                const int q = qb * 32 + mt * 16 + quad * 4 + i;
                const int4 mm = *(const int4*)&mask[(size_t)q * SEQ + kb * 64 + 4 * c];
                if (mm.x) w |= 1u << (mt * 16 + i * 4 + 0);
                if (mm.y) w |= 1u << (mt * 16 + i * 4 + 1);
                if (mm.z) w |= 1u << (mt * 16 + i * 4 + 2);
                if (mm.w) w |= 1u << (mt * 16 + i * 4 + 3);
            }
        PM[(size_t)gid * 64 + lane] = w;
    } else {
        const int cid = (blk - 512) * 256 + tid;
        const int mat = cid / 12288;
        const int rem = cid - mat * 12288;
        const int k = rem >> 4, c4 = rem & 15;
        const float* Wm = (mat == 0) ? Wq : (mat == 1) ? Wk : Wv;
        float4 w = *(const float4*)&Wm[(size_t)k * 64 + c4 * 4];
        float wv4[4] = {w.x, w.y, w.z, w.w};
        #pragma unroll
        for (int j = 0; j < 4; ++j)
            Wt[(size_t)(mat * 64 + c4 * 4 + j) * WID + k] = f2b(wv4[j]);
    }
}

// ---------------------------------------------------------------------------
// proj: barrier-free MFMA GEMM.  512 blocks x 256 thr; block = 32 rows x 192
// cols; wave = 16 rows x 96 cols, FULL K (24 chunks of 32).  A-frags loaded
// DIRECTLY global->reg (lane c = row, quad = k-block: exact MFMA A layout),
// B-frags direct from L2-hot Wt.  Prefetch: x depth-3, W depth-2; loop fully
// unrolled; zero barriers in the K-loop.  Epilogue: stage the 32x192 bf16
// tile in LDS (R4 BUG FIX: St sized/indexed for 32 rows, not 64 — the 64-row
// writeback clobbered neighbor blocks' rows with uninitialized LDS), then
// fully-coalesced writes (Q/K: 128B/row; Vt: 64B runs per d).
// ---------------------------------------------------------------------------
__global__ __launch_bounds__(256, 2) void qkv_proj_kernel(
    const float* __restrict__ x, const unsigned short* __restrict__ Wt,
    const float* __restrict__ bq, const float* __restrict__ bk, const float* __restrict__ bv,
    unsigned short* __restrict__ Qg, unsigned short* __restrict__ Kg,
    unsigned short* __restrict__ Vtg)
{
    __shared__ unsigned short St[32][200];

    const int tid = threadIdx.x;
    const int wv = tid >> 6, lane = tid & 63, quad = lane >> 4, c = lane & 15;
    const int rowb = blockIdx.x * 32;
    const int row0 = rowb + (wv >> 1) * 16;       // wave's 16 rows
    const int c0   = (wv & 1) * 96;               // wave's col half

    float bias[6];
    #pragma unroll
    for (int nt = 0; nt < 6; ++nt) {
        int col = c0 + nt * 16 + c;
        const float* B = (col < 64) ? bq : (col < 128) ? bk : bv;
        bias[nt] = B[col & 63];
    }

    const float* xrow = x + (size_t)(row0 + c) * WID + quad * 8;
    const unsigned short* wbase = Wt + (size_t)quad * 8;

    f32x4 acc[6];
    #pragma unroll
    for (int nt = 0; nt < 6; ++nt) acc[nt] = zero4();

    float4 pxa[3], pxb[3];
    uint4  pw[2][6];
    #pragma unroll
    for (int u = 0; u < 3; ++u) {
        pxa[u] = *(const float4*)&xrow[u * 32];
        pxb[u] = *(const float4*)&xrow[u * 32 + 4];
    }
    #pragma unroll
    for (int u = 0; u < 2; ++u)
        #pragma unroll
        for (int nt = 0; nt < 6; ++nt)
            pw[u][nt] = *(const uint4*)&wbase[(size_t)(c0 + nt * 16 + c) * WID + u * 32];

    #pragma unroll
    for (int kc = 0; kc < 24; ++kc) {
        union { uint4 u; s8v v; } af;
        af.u.x = packRNE(pxa[kc % 3].x, pxa[kc % 3].y);
        af.u.y = packRNE(pxa[kc % 3].z, pxa[kc % 3].w);
        af.u.z = packRNE(pxb[kc % 3].x, pxb[kc % 3].y);
        af.u.w = packRNE(pxb[kc % 3].z, pxb[kc % 3].w);
        union { uint4 u; s8v v; } bf[6];
        #pragma unroll
        for (int nt = 0; nt < 6; ++nt) bf[nt].u = pw[kc & 1][nt];

        if (kc + 3 < 24) {
            pxa[kc % 3] = *(const float4*)&xrow[(kc + 3) * 32];
            pxb[kc % 3] = *(const float4*)&xrow[(kc + 3) * 32 + 4];
        }
        if (kc + 2 < 24) {
            #pragma unroll
            for (int nt = 0; nt < 6; ++nt)
                pw[kc & 1][nt] = *(const uint4*)&wbase[(size_t)(c0 + nt * 16 + c) * WID + (kc + 2) * 32];
        }

        #pragma unroll
        for (int nt = 0; nt < 6; ++nt)
            acc[nt] = __builtin_amdgcn_mfma_f32_16x16x32_bf16(af.v, bf[nt].v, acc[nt], 0, 0, 0);
    }

    // ---- epilogue: bias + stage bf16 tile in LDS (C-layout scatter)
    #pragma unroll
    for (int nt = 0; nt < 6; ++nt)
        #pragma unroll
        for (int i = 0; i < 4; ++i)
            St[(wv >> 1) * 16 + quad * 4 + i][c0 + nt * 16 + c] = f2b(acc[nt][i] + bias[nt]);
    __syncthreads();

    // Q/K: 32 rows x 128B contiguous per matrix (one uint4 per thread each)
    {
        const int r = tid >> 3, g8 = (tid & 7) * 8;
        uint4 q = *(uint4*)&St[r][g8];
        uint4 k = *(uint4*)&St[r][64 + g8];
        *(uint4*)&Qg[(size_t)(rowb + r) * 64 + g8] = q;
        *(uint4*)&Kg[(size_t)(rowb + r) * 64 + g8] = k;
    }
    // V transposed: 64 d x 32 tok; thread d = tid>>2, j = tid&3 packs 8 toks
    {
        const int bt = rowb >> 11, tok0 = rowb & 2047;
        const int d = tid >> 2, j = tid & 3;
        unsigned short p[8];
        #pragma unroll
        for (int s = 0; s < 8; ++s) p[s] = St[j * 8 + s][128 + d];
        uint4 w;
        w.x = (unsigned)p[0] | ((unsigned)p[1] << 16);
        w.y = (unsigned)p[2] | ((unsigned)p[3] << 16);
        w.z = (unsigned)p[4] | ((unsigned)p[5] << 16);
        w.w = (unsigned)p[6] | ((unsigned)p[7] << 16);
        *(uint4*)&Vtg[((size_t)bt * 64 + d) * SEQ + tok0 + j * 8] = w;
    }
}

// ---------------------------------------------------------------------------
// attn: flash attention, MFMA bf16, fixed-shift softmax (p = 2^(s*0.125/ln2
// - 15/ln2); exact after the final divide by l).  Block 512 thr = 8 waves =
// 8 key-slices of 256; each wave: 32 q x 64 keys x 4 iters, NO barriers in
// the K-loop, K/PM prefetched one iter ahead, V loaded per iter (latency
// overlaps S-GEMM).  16 waves/CU.  P truncate-packed; l accumulated from the
// same truncated bits.  8-way slice merge via padded-LDS atomics.
// ---------------------------------------------------------------------------
__global__ __launch_bounds__(512, 4) void attn_kernel(
    const unsigned short* __restrict__ Qg, const unsigned short* __restrict__ Kg,
    const unsigned short* __restrict__ Vtg, const unsigned* __restrict__ PM,
    float* __restrict__ out)
{
    __shared__ unsigned short Ps[8][32][72];
    __shared__ float Obuf[32][68];
    __shared__ float Lbuf[32];

    const int tid = threadIdx.x;
    const int wv = tid >> 6, lane = tid & 63, quad = lane >> 4, c = lane & 15;
    const int sl = wv;                       // key slice 0..7
    const int qt = blockIdx.x, bb = blockIdx.y;
    const size_t qrow0 = (size_t)bb * SEQ + qt * 32;

    // zero merge buffers
    #pragma unroll
    for (int j = 0; j < 5; ++j) {
        int idx = tid + 512 * j;
        if (idx < 32 * 68) ((float*)Obuf)[idx] = 0.f;
    }
    if (tid < 32) Lbuf[tid] = 0.f;

    // Q fragments direct from global
    s8v qf[2][2];
    #pragma unroll
    for (int mt = 0; mt < 2; ++mt)
        #pragma unroll
        for (int ks = 0; ks < 2; ++ks)
            qf[mt][ks] = *(const s8v*)&Qg[(qrow0 + mt * 16 + c) * 64 + ks * 32 + quad * 8];

    const unsigned short* Kb = Kg + (size_t)bb * SEQ * 64;
    const unsigned short* Vb = Vtg + (size_t)bb * 64 * SEQ;

    f32x4 O[2][4];
    float lro[2][4];
    #pragma unroll
    for (int mt = 0; mt < 2; ++mt)
        #pragma unroll
        for (int nt = 0; nt < 4; ++nt) O[mt][nt] = zero4();
    #pragma unroll
    for (int mt = 0; mt < 2; ++mt)
        #pragma unroll
        for (int i = 0; i < 4; ++i) lro[mt][i] = 0.f;

    // prefetch K frags + PM for kt=0
    s8v kf[8];
    #pragma unroll
    for (int ks = 0; ks < 2; ++ks)
        #pragma unroll
        for (int nt = 0; nt < 4; ++nt)
            kf[ks * 4 + nt] = *(const s8v*)&Kb[(size_t)(sl * 256 + 4 * c + nt) * 64 + ks * 32 + quad * 8];
    unsigned pm = PM[(size_t)(qt * 32 + sl * 4) * 64 + lane];

    #pragma unroll
    for (int kt = 0; kt < 4; ++kt) {
        const int kbase = sl * 256 + kt * 64;

        s8v vf[8];
        #pragma unroll
        for (int ks = 0; ks < 2; ++ks)
            #pragma unroll
            for (int nt = 0; nt < 4; ++nt)
                vf[ks * 4 + nt] = *(const s8v*)&Vb[(size_t)(nt * 16 + c) * SEQ + kbase + ks * 32 + quad * 8];

        f32x4 S[2][4];
        #pragma unroll
        for (int mt = 0; mt < 2; ++mt)
            #pragma unroll
            for (int nt = 0; nt < 4; ++nt) S[mt][nt] = zero4();
        #pragma unroll
        for (int ks = 0; ks < 2; ++ks)
            #pragma unroll
            for (int nt = 0; nt < 4; ++nt) {
                S[0][nt] = __builtin_amdgcn_mfma_f32_16x16x32_bf16(qf[0][ks], kf[ks * 4 + nt], S[0][nt], 0, 0, 0);
                S[1][nt] = __builtin_amdgcn_mfma_f32_16x16x32_bf16(qf[1][ks], kf[ks * 4 + nt], S[1][nt], 0, 0, 0);
            }

        // prefetch next-iter K + PM (wrap)
        {
            const int ktn = (kt + 1) & 3;
            const int kbn = sl * 256 + ktn * 64;
            #pragma unroll
            for (int ks = 0; ks < 2; ++ks)
                #pragma unroll
                for (int nt = 0; nt < 4; ++nt)
                    kf[ks * 4 + nt] = *(const s8v*)&Kb[(size_t)(kbn + 4 * c + nt) * 64 + ks * 32 + quad * 8];
        }
        const unsigned pmN = PM[(size_t)(qt * 32 + sl * 4 + ((kt + 1) & 3)) * 64 + lane];

        // fixed-shift softmax: p = 2^(s*0.18034 - 21.6404), masked -> 0
        #pragma unroll
        for (int mt = 0; mt < 2; ++mt)
            #pragma unroll
            for (int i = 0; i < 4; ++i) {
                float p4[4];
                #pragma unroll
                for (int nt = 0; nt < 4; ++nt) {
                    float e = exp2f(fmaf(S[mt][nt][i], 0.18033688011112042f, -21.640425613334451f));
                    p4[nt] = ((pm >> (mt * 16 + i * 4 + nt)) & 1u) ? e : 0.f;
                }
                unsigned u0 = packTRUNC(p4[0], p4[1]);
                unsigned u1 = packTRUNC(p4[2], p4[3]);
                lro[mt][i] += bitsf(u0 << 16) + bitsf(u0 & 0xFFFF0000u)
                            + bitsf(u1 << 16) + bitsf(u1 & 0xFFFF0000u);
                *(uint2*)&Ps[wv][mt * 16 + quad * 4 + i][4 * c] = make_uint2(u0, u1);
            }
        pm = pmN;

        // O += P V
        #pragma unroll
        for (int ks = 0; ks < 2; ++ks) {
            s8v a0 = *(const s8v*)&Ps[wv][c][ks * 32 + quad * 8];
            s8v a1 = *(const s8v*)&Ps[wv][16 + c][ks * 32 + quad * 8];
            #pragma unroll
            for (int nt = 0; nt < 4; ++nt) {
                O[0][nt] = __builtin_amdgcn_mfma_f32_16x16x32_bf16(a0, vf[ks * 4 + nt], O[0][nt], 0, 0, 0);
                O[1][nt] = __builtin_amdgcn_mfma_f32_16x16x32_bf16(a1, vf[ks * 4 + nt], O[1][nt], 0, 0, 0);
            }
        }
    }

    // ---- merge 8 slices
    __syncthreads();   // orders zeroing (pre-loop) before atomics, all waves
    #pragma unroll
    for (int mt = 0; mt < 2; ++mt)
        #pragma unroll
        for (int i = 0; i < 4; ++i) {
            float l = lro[mt][i];
            l += __shfl_xor(l, 1);
            l += __shfl_xor(l, 2);
            l += __shfl_xor(l, 4);
            l += __shfl_xor(l, 8);
            if (c == 0) atomicAdd(&Lbuf[mt * 16 + quad * 4 + i], l);
            #pragma unroll
            for (int nt = 0; nt < 4; ++nt)
                atomicAdd(&Obuf[mt * 16 + quad * 4 + i][nt * 16 + c], O[mt][nt][i]);
        }
    __syncthreads();
    {
        const int r = tid >> 4, d4 = (tid & 15) * 4;
        const float invL = 1.0f / Lbuf[r];
        float4 v = *(float4*)&Obuf[r][d4];
        float4 o = make_float4(v.x * invL, v.y * invL, v.z * invL, v.w * invL);
        *(float4*)&out[(qrow0 + r) * 64 + d4] = o;
    }
}

extern "C" void kernel_launch(void* const* d_in, const int* in_sizes, int n_in,
                              void* d_out, int out_size, void* d_ws, size_t ws_size,
                              hipStream_t stream)
{
    const float* x    = (const float*)d_in[0];
    const float* Wq   = (const float*)d_in[1];
    const float* bq   = (const float*)d_in[2];
    const float* Wk   = (const float*)d_in[3];
    const float* bk   = (const float*)d_in[4];
    const float* Wv   = (const float*)d_in[5];
    const float* bv   = (const float*)d_in[6];
    const int*   mask = (const int*)d_in[7];
    float* out = (float*)d_out;

    unsigned short* Qg  = (unsigned short*)d_ws;
    unsigned short* Kg  = Qg + (size_t)16384 * 64;
    unsigned short* Vtg = Kg + (size_t)16384 * 64;
    unsigned short* Wt  = Vtg + (size_t)16384 * 64;
    unsigned*       PM  = (unsigned*)(Wt + (size_t)192 * WID);

    prep_kernel<<<656, 256, 0, stream>>>(mask, Wq, Wk, Wv, PM, Wt);
    qkv_proj_kernel<<<512, 256, 0, stream>>>(x, Wt, bq, bk, bv, Qg, Kg, Vtg);
    attn_kernel<<<dim3(64, 8), 512, 0, stream>>>(Qg, Kg, Vtg, PM, out);
}

// Round 6
// 192.544 us; speedup vs baseline: 1.1654x; 1.1654x over previous
//
#include <hip/hip_runtime.h>

typedef short  s8v   __attribute__((ext_vector_type(8)));
typedef float  f32x4 __attribute__((ext_vector_type(4)));

#define SEQ 2048
#define WID 768

__device__ __forceinline__ unsigned fbits(float f) {
    union { float f; unsigned u; } v; v.f = f; return v.u;
}
__device__ __forceinline__ float bitsf(unsigned u) {
    union { unsigned u; float f; } v; v.u = u; return v.f;
}
__device__ __forceinline__ unsigned short f2b(float f) {
    unsigned u = fbits(f);
    return (unsigned short)((u + 0x7FFFu + ((u >> 16) & 1u)) >> 16);   // RNE
}
__device__ __forceinline__ unsigned packRNE(float a, float b) {
    unsigned ta = fbits(a) + 0x7FFFu + ((fbits(a) >> 16) & 1u);
    unsigned tb = fbits(b) + 0x7FFFu + ((fbits(b) >> 16) & 1u);
    return __builtin_amdgcn_perm(tb, ta, 0x07060302u);
}
__device__ __forceinline__ unsigned packTRUNC(float a, float b) {
    return __builtin_amdgcn_perm(fbits(b), fbits(a), 0x07060302u);
}
__device__ __forceinline__ f32x4 zero4() { f32x4 z = {0.f, 0.f, 0.f, 0.f}; return z; }

// async global->LDS DMA, 16B per lane; LDS dest = uniform base + lane*16
__device__ __forceinline__ void async16(const unsigned short* g, unsigned short* l) {
    __builtin_amdgcn_global_load_lds(
        (const __attribute__((address_space(1))) unsigned int*)g,
        (__attribute__((address_space(3))) unsigned int*)l, 16, 0, 0);
}

// ---------------------------------------------------------------------------
// prep (verbatim, verified): PM mask-bit packing + W transpose to bf16.
// ---------------------------------------------------------------------------
__global__ __launch_bounds__(256) void prep_kernel(
    const int* __restrict__ mask,
    const float* __restrict__ Wq, const float* __restrict__ Wk, const float* __restrict__ Wv,
    unsigned* __restrict__ PM, unsigned short* __restrict__ Wt)
{
    const int tid = threadIdx.x;
    const int blk = blockIdx.x;
    if (blk < 512) {
        const int gid  = blk * 4 + (tid >> 6);
        const int lane = tid & 63, quad = lane >> 4, c = lane & 15;
        const int qb = gid >> 5, kb = gid & 31;
        unsigned w = 0;
        #pragma unroll
        for (int mt = 0; mt < 2; ++mt)
            #pragma unroll
            for (int i = 0; i < 4; ++i) {
                const int q = qb * 32 + mt * 16 + quad * 4 + i;
                const int4 mm = *(const int4*)&mask[(size_t)q * SEQ + kb * 64 + 4 * c];
                if (mm.x) w |= 1u << (mt * 16 + i * 4 + 0);
                if (mm.y) w |= 1u << (mt * 16 + i * 4 + 1);
                if (mm.z) w |= 1u << (mt * 16 + i * 4 + 2);
                if (mm.w) w |= 1u << (mt * 16 + i * 4 + 3);
            }
        PM[(size_t)gid * 64 + lane] = w;
    } else {
        const int cid = (blk - 512) * 256 + tid;
        const int mat = cid / 12288;
        const int rem = cid - mat * 12288;
        const int k = rem >> 4, c4 = rem & 15;
        const float* Wm = (mat == 0) ? Wq : (mat == 1) ? Wk : Wv;
        float4 w = *(const float4*)&Wm[(size_t)k * 64 + c4 * 4];
        float wv4[4] = {w.x, w.y, w.z, w.w};
        #pragma unroll
        for (int j = 0; j < 4; ++j)
            Wt[(size_t)(mat * 64 + c4 * 4 + j) * WID + k] = f2b(wv4[j]);
    }
}

// ---------------------------------------------------------------------------
// proj: barrier-free MFMA GEMM (K-loop identical to R5, verified).  Epilogue
// now emits FRAG-TILED layouts so attn reads are contiguous 1KB bursts:
//  QF[qgrp16][ks][lane]x8 : Q[qbase+c][ks*32+quad*8+j]
//  KF[kb64][ks*4+nt][lane]x8 : K[kb*64+4c+nt][ks*32+quad*8+j]   (B-frag for S)
//  VF[kb64][ks*4+nt][lane]x8 : V^T[nt*16+c][kb*64+ks*32+quad*8+j] (B-frag PV)
// ---------------------------------------------------------------------------
__global__ __launch_bounds__(256, 2) void qkv_proj_kernel(
    const float* __restrict__ x, const unsigned short* __restrict__ Wt,
    const float* __restrict__ bq, const float* __restrict__ bk, const float* __restrict__ bv,
    unsigned short* __restrict__ QF, unsigned short* __restrict__ KF,
    unsigned short* __restrict__ VF)
{
    __shared__ unsigned short St[32][208];   // 416B rows: 16B-aligned

    const int tid = threadIdx.x;
    const int wv = tid >> 6, lane = tid & 63, quad = lane >> 4, c = lane & 15;
    const int rowb = blockIdx.x * 32;
    const int row0 = rowb + (wv >> 1) * 16;
    const int c0   = (wv & 1) * 96;

    float bias[6];
    #pragma unroll
    for (int nt = 0; nt < 6; ++nt) {
        int col = c0 + nt * 16 + c;
        const float* B = (col < 64) ? bq : (col < 128) ? bk : bv;
        bias[nt] = B[col & 63];
    }

    const float* xrow = x + (size_t)(row0 + c) * WID + quad * 8;
    const unsigned short* wbase = Wt + (size_t)quad * 8;

    f32x4 acc[6];
    #pragma unroll
    for (int nt = 0; nt < 6; ++nt) acc[nt] = zero4();

    float4 pxa[3], pxb[3];
    uint4  pw[2][6];
    #pragma unroll
    for (int u = 0; u < 3; ++u) {
        pxa[u] = *(const float4*)&xrow[u * 32];
        pxb[u] = *(const float4*)&xrow[u * 32 + 4];
    }
    #pragma unroll
    for (int u = 0; u < 2; ++u)
        #pragma unroll
        for (int nt = 0; nt < 6; ++nt)
            pw[u][nt] = *(const uint4*)&wbase[(size_t)(c0 + nt * 16 + c) * WID + u * 32];

    #pragma unroll
    for (int kc = 0; kc < 24; ++kc) {
        union { uint4 u; s8v v; } af;
        af.u.x = packRNE(pxa[kc % 3].x, pxa[kc % 3].y);
        af.u.y = packRNE(pxa[kc % 3].z, pxa[kc % 3].w);
        af.u.z = packRNE(pxb[kc % 3].x, pxb[kc % 3].y);
        af.u.w = packRNE(pxb[kc % 3].z, pxb[kc % 3].w);
        union { uint4 u; s8v v; } bf[6];
        #pragma unroll
        for (int nt = 0; nt < 6; ++nt) bf[nt].u = pw[kc & 1][nt];

        if (kc + 3 < 24) {
            pxa[kc % 3] = *(const float4*)&xrow[(kc + 3) * 32];
            pxb[kc % 3] = *(const float4*)&xrow[(kc + 3) * 32 + 4];
        }
        if (kc + 2 < 24) {
            #pragma unroll
            for (int nt = 0; nt < 6; ++nt)
                pw[kc & 1][nt] = *(const uint4*)&wbase[(size_t)(c0 + nt * 16 + c) * WID + (kc + 2) * 32];
        }

        #pragma unroll
        for (int nt = 0; nt < 6; ++nt)
            acc[nt] = __builtin_amdgcn_mfma_f32_16x16x32_bf16(af.v, bf[nt].v, acc[nt], 0, 0, 0);
    }

    // stage 32x192 bf16 tile in LDS
    #pragma unroll
    for (int nt = 0; nt < 6; ++nt)
        #pragma unroll
        for (int i = 0; i < 4; ++i)
            St[(wv >> 1) * 16 + quad * 4 + i][c0 + nt * 16 + c] = f2b(acc[nt][i] + bias[nt]);
    __syncthreads();

    const int kb  = rowb >> 6;               // 64-key tile index (global)
    const int c0k = (rowb & 63) >> 2;        // 0 or 8: key sub-range
    const int ks0 = (rowb & 63) >> 5;        // 0 or 1: V key-half

    // QF: 2 qg x 2 ks, 64 lanes each -> 1KB contiguous stores
    {
        const int qg = (tid >> 7) & 1, ks = (tid >> 6) & 1;
        const int l = tid & 63, qd = l >> 4, cc = l & 15;
        uint4 v = *(uint4*)&St[qg * 16 + cc][ks * 32 + qd * 8];
        *(uint4*)&QF[(((size_t)(rowb >> 4) + qg) * 2 + ks) * 512 + (size_t)l * 8] = v;
    }
    // KF: 8 (ks,nt) x 32 half-lanes -> 128B runs
    {
        const int ksnt = tid >> 5, u = tid & 31;
        const int ks = ksnt >> 2, nt = ksnt & 3;
        const int qd = u >> 3, cc = u & 7;
        uint4 v = *(uint4*)&St[4 * cc + nt][64 + ks * 32 + qd * 8];
        *(uint4*)&KF[(((size_t)kb * 8 + ksnt) * 64 + qd * 16 + c0k + cc) * 8] = v;
    }
    // VF: 4 nt x 64 lanes -> 1KB contiguous stores (gather St columns)
    {
        const int nt = tid >> 6, l = tid & 63, qd = l >> 4, cc = l & 15;
        unsigned short p[8];
        #pragma unroll
        for (int s = 0; s < 8; ++s) p[s] = St[qd * 8 + s][128 + nt * 16 + cc];
        uint4 w;
        w.x = (unsigned)p[0] | ((unsigned)p[1] << 16);
        w.y = (unsigned)p[2] | ((unsigned)p[3] << 16);
        w.z = (unsigned)p[4] | ((unsigned)p[5] << 16);
        w.w = (unsigned)p[6] | ((unsigned)p[7] << 16);
        *(uint4*)&VF[(((size_t)kb * 8 + ks0 * 4 + nt) * 64 + l) * 8] = w;
    }
}

// ---------------------------------------------------------------------------
// attn: flash attention, MFMA bf16, fixed-shift softmax.  Block = 1024 thr =
// 16 waves = 4 q-groups(16q) x 4 key-slices(512 keys); block = 64q x 2048k.
// Grid (32,8) = 256 blocks = 1/CU, 16 waves/CU = 4/SIMD.  Per iter each
// slice's 64-key K/V tile is DMA'd to LDS via global_load_lds (zero VGPR)
// and shared by its 4 q-waves.  Lean regs (~100): no spills.  P transposes
// through wave-private LDS; l accumulated from the same truncated bits.
// ---------------------------------------------------------------------------
__global__ __launch_bounds__(1024) void attn_kernel(
    const unsigned short* __restrict__ QF, const unsigned short* __restrict__ KF,
    const unsigned short* __restrict__ VF, const unsigned* __restrict__ PM,
    float* __restrict__ out)
{
    __shared__ unsigned short KVk[4][4096];   // 8KB per slice
    __shared__ unsigned short KVv[4][4096];
    __shared__ unsigned short Ps[16][16][72];
    __shared__ float Obuf[64][68];
    __shared__ float Lbuf[64];

    const int tid = threadIdx.x;
    const int wv = tid >> 6, lane = tid & 63, quad = lane >> 4, c = lane & 15;
    const int sl = wv & 3, qg = wv >> 2;
    const int mt = qg & 1;
    const int qt = blockIdx.x, bb = blockIdx.y;

    #pragma unroll
    for (int j = 0; j < 5; ++j) {
        int idx = tid + 1024 * j;
        if (idx < 64 * 68) ((float*)Obuf)[idx] = 0.f;
    }
    if (tid < 64) Lbuf[tid] = 0.f;

    // Q frags: 2 coalesced 1KB loads per wave
    s8v qf[2];
    {
        const size_t qgrp = (size_t)bb * 128 + qt * 4 + qg;
        #pragma unroll
        for (int ks = 0; ks < 2; ++ks)
            qf[ks] = *(const s8v*)&QF[(qgrp * 2 + ks) * 512 + (size_t)lane * 8];
    }

    f32x4 O[4];
    float lro[4];
    #pragma unroll
    for (int nt = 0; nt < 4; ++nt) O[nt] = zero4();
    #pragma unroll
    for (int i = 0; i < 4; ++i) lro[i] = 0.f;

    for (int kt = 0; kt < 8; ++kt) {
        const int kbg = bb * 32 + sl * 8 + kt;
        const unsigned short* bk = KF + (size_t)kbg * 4096;
        const unsigned short* bv = VF + (size_t)kbg * 4096;
        #pragma unroll
        for (int r = 0; r < 2; ++r) {
            const int cn = qg * 2 + r;
            async16(bk + cn * 512 + lane * 8, &KVk[sl][cn * 512]);
            async16(bv + cn * 512 + lane * 8, &KVv[sl][cn * 512]);
        }
        const unsigned pm = PM[(size_t)((qt * 2 + (qg >> 1)) * 32 + sl * 8 + kt) * 64 + lane];
        __syncthreads();   // drains DMA (vmcnt) + publishes LDS tiles

        // ---- S = Q K^T
        f32x4 S[4];
        #pragma unroll
        for (int nt = 0; nt < 4; ++nt) S[nt] = zero4();
        #pragma unroll
        for (int ks = 0; ks < 2; ++ks) {
            s8v kfr[4];
            #pragma unroll
            for (int nt = 0; nt < 4; ++nt)
                kfr[nt] = *(const s8v*)&KVk[sl][((ks * 4 + nt) * 64 + lane) * 8];
            #pragma unroll
            for (int nt = 0; nt < 4; ++nt)
                S[nt] = __builtin_amdgcn_mfma_f32_16x16x32_bf16(qf[ks], kfr[nt], S[nt], 0, 0, 0);
        }

        // ---- fixed-shift softmax: p = 2^(s*0.125/ln2 - 15/ln2)
        const unsigned pmh = pm >> (mt * 16);
        #pragma unroll
        for (int i = 0; i < 4; ++i) {
            float p4[4];
            #pragma unroll
            for (int nt = 0; nt < 4; ++nt) {
                float e = exp2f(fmaf(S[nt][i], 0.18033688011112042f, -21.640425613334451f));
                p4[nt] = ((pmh >> (i * 4 + nt)) & 1u) ? e : 0.f;
            }
            unsigned u0 = packTRUNC(p4[0], p4[1]);
            unsigned u1 = packTRUNC(p4[2], p4[3]);
            lro[i] += bitsf(u0 << 16) + bitsf(u0 & 0xFFFF0000u)
                    + bitsf(u1 << 16) + bitsf(u1 & 0xFFFF0000u);
            *(uint2*)&Ps[wv][quad * 4 + i][4 * c] = make_uint2(u0, u1);
        }

        // ---- O += P V
        #pragma unroll
        for (int ks = 0; ks < 2; ++ks) {
            s8v a = *(const s8v*)&Ps[wv][c][ks * 32 + quad * 8];
            s8v vfr[4];
            #pragma unroll
            for (int nt = 0; nt < 4; ++nt)
                vfr[nt] = *(const s8v*)&KVv[sl][((ks * 4 + nt) * 64 + lane) * 8];
            #pragma unroll
            for (int nt = 0; nt < 4; ++nt)
                O[nt] = __builtin_amdgcn_mfma_f32_16x16x32_bf16(a, vfr[nt], O[nt], 0, 0, 0);
        }
        __syncthreads();   // all reads of this tile done before next DMA
    }

    // ---- merge 4 slices per q-group
    #pragma unroll
    for (int i = 0; i < 4; ++i) {
        float l = lro[i];
        l += __shfl_xor(l, 1);
        l += __shfl_xor(l, 2);
        l += __shfl_xor(l, 4);
        l += __shfl_xor(l, 8);
        if (c == 0) atomicAdd(&Lbuf[qg * 16 + quad * 4 + i], l);
        #pragma unroll
        for (int nt = 0; nt < 4; ++nt)
            atomicAdd(&Obuf[qg * 16 + quad * 4 + i][nt * 16 + c], O[nt][i]);
    }
    __syncthreads();
    {
        const int r = tid >> 4, d4 = (tid & 15) * 4;
        const float invL = 1.0f / Lbuf[r];
        float4 v = *(float4*)&Obuf[r][d4];
        float4 o = make_float4(v.x * invL, v.y * invL, v.z * invL, v.w * invL);
        *(float4*)&out[((size_t)bb * SEQ + qt * 64 + r) * 64 + d4] = o;
    }
}

extern "C" void kernel_launch(void* const* d_in, const int* in_sizes, int n_in,
                              void* d_out, int out_size, void* d_ws, size_t ws_size,
                              hipStream_t stream)
{
    const float* x    = (const float*)d_in[0];
    const float* Wq   = (const float*)d_in[1];
    const float* bq   = (const float*)d_in[2];
    const float* Wk   = (const float*)d_in[3];
    const float* bk   = (const float*)d_in[4];
    const float* Wv   = (const float*)d_in[5];
    const float* bv   = (const float*)d_in[6];
    const int*   mask = (const int*)d_in[7];
    float* out = (float*)d_out;

    unsigned short* QF = (unsigned short*)d_ws;
    unsigned short* KF = QF + (size_t)16384 * 64;
    unsigned short* VF = KF + (size_t)16384 * 64;
    unsigned short* Wt = VF + (size_t)16384 * 64;
    unsigned*       PM = (unsigned*)(Wt + (size_t)192 * WID);

    prep_kernel<<<656, 256, 0, stream>>>(mask, Wq, Wk, Wv, PM, Wt);
    qkv_proj_kernel<<<512, 256, 0, stream>>>(x, Wt, bq, bk, bv, QF, KF, VF);
    attn_kernel<<<dim3(32, 8), 1024, 0, stream>>>(QF, KF, VF, PM, out);
}

// Round 7
// 188.084 us; speedup vs baseline: 1.1931x; 1.0237x over previous
//
#include <hip/hip_runtime.h>

typedef short  s8v   __attribute__((ext_vector_type(8)));
typedef float  f32x4 __attribute__((ext_vector_type(4)));

#define SEQ 2048
#define WID 768

__device__ __forceinline__ unsigned fbits(float f) {
    union { float f; unsigned u; } v; v.f = f; return v.u;
}
__device__ __forceinline__ float bitsf(unsigned u) {
    union { unsigned u; float f; } v; v.u = u; return v.f;
}
__device__ __forceinline__ unsigned short f2b(float f) {
    unsigned u = fbits(f);
    return (unsigned short)((u + 0x7FFFu + ((u >> 16) & 1u)) >> 16);   // RNE
}
__device__ __forceinline__ unsigned packRNE(float a, float b) {
    unsigned ta = fbits(a) + 0x7FFFu + ((fbits(a) >> 16) & 1u);
    unsigned tb = fbits(b) + 0x7FFFu + ((fbits(b) >> 16) & 1u);
    return __builtin_amdgcn_perm(tb, ta, 0x07060302u);
}
__device__ __forceinline__ unsigned packTRUNC(float a, float b) {
    return __builtin_amdgcn_perm(fbits(b), fbits(a), 0x07060302u);
}
__device__ __forceinline__ f32x4 zero4() { f32x4 z = {0.f, 0.f, 0.f, 0.f}; return z; }

// async global->LDS DMA, 16B/lane; g already includes lane*16B, LDS base uniform
__device__ __forceinline__ void async16(const unsigned short* g, unsigned short* l) {
    __builtin_amdgcn_global_load_lds(
        (const __attribute__((address_space(1))) unsigned int*)g,
        (__attribute__((address_space(3))) unsigned int*)l, 16, 0, 0);
}
__device__ __forceinline__ void async16f(const float* g, float* l) {
    __builtin_amdgcn_global_load_lds(
        (const __attribute__((address_space(1))) unsigned int*)g,
        (__attribute__((address_space(3))) unsigned int*)l, 16, 0, 0);
}

// ---------------------------------------------------------------------------
// prep (verbatim, verified): PM mask-bit packing + W transpose to bf16.
// ---------------------------------------------------------------------------
__global__ __launch_bounds__(256) void prep_kernel(
    const int* __restrict__ mask,
    const float* __restrict__ Wq, const float* __restrict__ Wk, const float* __restrict__ Wv,
    unsigned* __restrict__ PM, unsigned short* __restrict__ Wt)
{
    const int tid = threadIdx.x;
    const int blk = blockIdx.x;
    if (blk < 512) {
        const int gid  = blk * 4 + (tid >> 6);
        const int lane = tid & 63, quad = lane >> 4, c = lane & 15;
        const int qb = gid >> 5, kb = gid & 31;
        unsigned w = 0;
        #pragma unroll
        for (int mt = 0; mt < 2; ++mt)
            #pragma unroll
            for (int i = 0; i < 4; ++i) {
                const int q = qb * 32 + mt * 16 + quad * 4 + i;
                const int4 mm = *(const int4*)&mask[(size_t)q * SEQ + kb * 64 + 4 * c];
                if (mm.x) w |= 1u << (mt * 16 + i * 4 + 0);
                if (mm.y) w |= 1u << (mt * 16 + i * 4 + 1);
                if (mm.z) w |= 1u << (mt * 16 + i * 4 + 2);
                if (mm.w) w |= 1u << (mt * 16 + i * 4 + 3);
            }
        PM[(size_t)gid * 64 + lane] = w;
    } else {
        const int cid = (blk - 512) * 256 + tid;
        const int mat = cid / 12288;
        const int rem = cid - mat * 12288;
        const int k = rem >> 4, c4 = rem & 15;
        const float* Wm = (mat == 0) ? Wq : (mat == 1) ? Wk : Wv;
        float4 w = *(const float4*)&Wm[(size_t)k * 64 + c4 * 4];
        float wv4[4] = {w.x, w.y, w.z, w.w};
        #pragma unroll
        for (int j = 0; j < 4; ++j)
            Wt[(size_t)(mat * 64 + c4 * 4 + j) * WID + k] = f2b(wv4[j]);
    }
}

// ---------------------------------------------------------------------------
// proj: burst-DMA MFMA GEMM.  1024 blocks x 256 thr (3 blocks/CU @48KB LDS).
// Block tile = 16 rows x 192 cols (wave = 16 x 48).  Phase 0: the block's
// 16x768 fp32 x-tile is ONE contiguous 48KB region -> 48 global_load_lds
// issued back-to-back (12/wave), one barrier: pure HBM-BW drain, scheduler-
// proof.  Phase 1: repack to padded bf16 Xb[16][776] (conflict-free b128 in
// the K-loop, zero packing VALU there).  Phase 2: 24 chunks x (1 ds_read +
// 3 L2 B-loads + 3 MFMA), no barriers.  Epilogue: R6's verified frag-tiled
// QF/KF/VF writeback re-indexed for 16-row blocks.
// ---------------------------------------------------------------------------
__global__ __launch_bounds__(256, 4) void qkv_proj_kernel(
    const float* __restrict__ x, const unsigned short* __restrict__ Wt,
    const float* __restrict__ bq, const float* __restrict__ bk, const float* __restrict__ bv,
    unsigned short* __restrict__ QF, unsigned short* __restrict__ KF,
    unsigned short* __restrict__ VF)
{
    __shared__ __align__(16) unsigned char SMEM[49152];
    float (*Xs)[WID]           = (float(*)[WID])SMEM;                       // 16x768 fp32
    unsigned short (*Xb)[776]  = (unsigned short(*)[776])(SMEM + 8192);     // bf16 padded
    unsigned short (*St)[208]  = (unsigned short(*)[208])SMEM;              // post-loop

    const int tid = threadIdx.x;
    const int wv = tid >> 6, lane = tid & 63, quad = lane >> 4, c = lane & 15;
    const int rowb = blockIdx.x * 16;
    const int c0w  = wv * 48;

    // ---- phase 0: burst DMA (48 x 1KB, contiguous)
    const float* xsrc = x + (size_t)rowb * WID;
    #pragma unroll
    for (int t = 0; t < 12; ++t) {
        const int d = wv * 12 + t;
        async16f(xsrc + d * 256 + lane * 4, (float*)SMEM + d * 256);
    }

    float bias[3];
    #pragma unroll
    for (int nt = 0; nt < 3; ++nt) {
        int col = c0w + nt * 16 + c;
        const float* B = (col < 64) ? bq : (col < 128) ? bk : bv;
        bias[nt] = B[col & 63];
    }
    __syncthreads();   // DMA drained (vmcnt) + published

    // ---- phase 1: repack fp32 -> padded bf16 (all fp32 to regs, barrier, write)
    {
        const int r = tid >> 4, cc0 = (tid & 15) * 48;
        float4 f[12];
        #pragma unroll
        for (int j = 0; j < 12; ++j) f[j] = *(float4*)&Xs[r][cc0 + 4 * j];
        __syncthreads();   // all fp32 consumed; Xb overlay now safe
        #pragma unroll
        for (int j = 0; j < 6; ++j) {
            uint4 w;
            w.x = packRNE(f[2*j].x,   f[2*j].y);
            w.y = packRNE(f[2*j].z,   f[2*j].w);
            w.z = packRNE(f[2*j+1].x, f[2*j+1].y);
            w.w = packRNE(f[2*j+1].z, f[2*j+1].w);
            *(uint4*)&Xb[r][cc0 + 8 * j] = w;
        }
    }
    __syncthreads();

    // ---- phase 2: K-loop, no barriers
    f32x4 acc[3];
    #pragma unroll
    for (int nt = 0; nt < 3; ++nt) acc[nt] = zero4();

    uint4 pw[2][3];
    #pragma unroll
    for (int u = 0; u < 2; ++u)
        #pragma unroll
        for (int nt = 0; nt < 3; ++nt)
            pw[u][nt] = *(const uint4*)&Wt[(size_t)(c0w + nt * 16 + c) * WID + u * 32 + quad * 8];

    #pragma unroll
    for (int kc = 0; kc < 24; ++kc) {
        s8v af = *(const s8v*)&Xb[c][kc * 32 + quad * 8];
        union { uint4 u; s8v v; } bf[3];
        #pragma unroll
        for (int nt = 0; nt < 3; ++nt) bf[nt].u = pw[kc & 1][nt];
        if (kc + 2 < 24) {
            #pragma unroll
            for (int nt = 0; nt < 3; ++nt)
                pw[kc & 1][nt] = *(const uint4*)&Wt[(size_t)(c0w + nt * 16 + c) * WID + (kc + 2) * 32 + quad * 8];
        }
        #pragma unroll
        for (int nt = 0; nt < 3; ++nt)
            acc[nt] = __builtin_amdgcn_mfma_f32_16x16x32_bf16(af, bf[nt].v, acc[nt], 0, 0, 0);
    }

    // ---- epilogue: stage 16x192 bf16 tile (St overlays dead fp32 region)
    #pragma unroll
    for (int nt = 0; nt < 3; ++nt)
        #pragma unroll
        for (int i = 0; i < 4; ++i)
            St[quad * 4 + i][c0w + nt * 16 + c] = f2b(acc[nt][i] + bias[nt]);
    __syncthreads();

    const int kb  = rowb >> 6;
    const int q0k = (rowb & 63) >> 2;    // KF c-offset (q0*4)
    const int ks0 = (rowb & 63) >> 5;    // VF ks half
    const int qd0 = (rowb & 31) >> 3;    // VF qd base (0 or 2)

    if (tid < 128) {   // QF: frag rows = block rows
        const int ks = tid >> 6, l = tid & 63, qd = l >> 4, cc = l & 15;
        uint4 v = *(uint4*)&St[cc][ks * 32 + qd * 8];
        *(uint4*)&QF[(((size_t)(rowb >> 4)) * 2 + ks) * 512 + (size_t)l * 8] = v;
    } else {           // KF
        const int u = tid - 128;
        const int ks = u >> 6, nt = (u >> 4) & 3, qd = (u >> 2) & 3, cc = u & 3;
        uint4 v = *(uint4*)&St[4 * cc + nt][64 + ks * 32 + qd * 8];
        *(uint4*)&KF[(((size_t)kb * 8 + ks * 4 + nt) * 64 + qd * 16 + q0k + cc) * 8] = v;
    }
    if (tid < 128) {   // VF
        const int d = tid >> 1, jj = tid & 1, qd = qd0 + jj;
        const int nt = d >> 4, cc = d & 15;
        unsigned short p[8];
        #pragma unroll
        for (int s = 0; s < 8; ++s) p[s] = St[jj * 8 + s][128 + d];
        uint4 w;
        w.x = (unsigned)p[0] | ((unsigned)p[1] << 16);
        w.y = (unsigned)p[2] | ((unsigned)p[3] << 16);
        w.z = (unsigned)p[4] | ((unsigned)p[5] << 16);
        w.w = (unsigned)p[6] | ((unsigned)p[7] << 16);
        *(uint4*)&VF[(((size_t)kb * 8 + ks0 * 4 + nt) * 64 + qd * 16 + cc) * 8] = w;
    }
}

// ---------------------------------------------------------------------------
// attn: flash attention, MFMA bf16, fixed-shift softmax.  1024 thr = 16 waves
// = 4 q-groups x 4 key-slices; grid 256 (XCD swizzle bb = blk&7 so each XCD's
// L2 holds one batch's K/V).  m97-shaped K-loop: double-buffered K DMA issued
// BEFORE compute, drained at the NEXT top-barrier -> DMA overlaps a full
// compute phase; one barrier/iter.  V frags direct per-wave register loads
// (issued under the S-MFMA shadow).  Ps and Obuf share one LDS region
// (union, time-separated by barriers).  LDS ~103 KB, 1 block/CU.
// ---------------------------------------------------------------------------
__global__ __launch_bounds__(1024, 4) void attn_kernel(
    const unsigned short* __restrict__ QF, const unsigned short* __restrict__ KF,
    const unsigned short* __restrict__ VF, const unsigned* __restrict__ PM,
    float* __restrict__ out)
{
    __shared__ unsigned short KVk[2][4][4096];          // 64 KB, K double-buffer
    __shared__ __align__(16) unsigned char PsOb[36864]; // Ps (36.9KB) ∪ Obuf (17.4KB)
    __shared__ float Lbuf[64];
    unsigned short (*Ps)[16][72] = (unsigned short(*)[16][72])PsOb;
    float (*Obuf)[68]            = (float(*)[68])PsOb;

    const int tid = threadIdx.x;
    const int wv = tid >> 6, lane = tid & 63, quad = lane >> 4, c = lane & 15;
    const int sl = wv & 3, qg = wv >> 2, mt = qg & 1;
    const int blk = blockIdx.x;
    const int bb = blk & 7, qt = blk >> 3;
    const size_t qrow0 = (size_t)bb * SEQ + qt * 64;

    if (tid < 64) Lbuf[tid] = 0.f;

    // Q frags (coalesced 1KB loads)
    s8v qf[2];
    {
        const size_t qgrp = (size_t)bb * 128 + qt * 4 + qg;
        #pragma unroll
        for (int ks = 0; ks < 2; ++ks)
            qf[ks] = *(const s8v*)&QF[(qgrp * 2 + ks) * 512 + (size_t)lane * 8];
    }

    f32x4 O[4];
    float lro[4];
    #pragma unroll
    for (int nt = 0; nt < 4; ++nt) O[nt] = zero4();
    #pragma unroll
    for (int i = 0; i < 4; ++i) lro[i] = 0.f;

    // prologue: DMA K tile kt=0 into buf 0
    {
        const size_t kbg = (size_t)bb * 32 + sl * 8;
        #pragma unroll
        for (int r = 0; r < 2; ++r) {
            const int cn = qg * 2 + r;
            async16(KF + kbg * 4096 + cn * 512 + lane * 8, &KVk[0][sl][cn * 512]);
        }
    }
    unsigned pm = PM[(size_t)((qt * 2 + (qg >> 1)) * 32 + sl * 8) * 64 + lane];

    for (int kt = 0; kt < 8; ++kt) {
        __syncthreads();   // publishes KVk[kt&1] (drains DMA issued last iter)

        if (kt < 7) {      // DMA next K tile; drains at NEXT barrier -> overlapped
            const size_t kbg = (size_t)bb * 32 + sl * 8 + kt + 1;
            #pragma unroll
            for (int r = 0; r < 2; ++r) {
                const int cn = qg * 2 + r;
                async16(KF + kbg * 4096 + cn * 512 + lane * 8, &KVk[(kt + 1) & 1][sl][cn * 512]);
            }
        }
        const unsigned pmN = (kt < 7)
            ? PM[(size_t)((qt * 2 + (qg >> 1)) * 32 + sl * 8 + kt + 1) * 64 + lane] : 0u;

        // ---- S = Q K^T from LDS tile
        f32x4 S[4];
        #pragma unroll
        for (int nt = 0; nt < 4; ++nt) S[nt] = zero4();
        #pragma unroll
        for (int ks = 0; ks < 2; ++ks) {
            s8v kfr[4];
            #pragma unroll
            for (int nt = 0; nt < 4; ++nt)
                kfr[nt] = *(const s8v*)&KVk[kt & 1][sl][((ks * 4 + nt) * 64 + lane) * 8];
            #pragma unroll
            for (int nt = 0; nt < 4; ++nt)
                S[nt] = __builtin_amdgcn_mfma_f32_16x16x32_bf16(qf[ks], kfr[nt], S[nt], 0, 0, 0);
        }

        // ---- V frags direct from global (latency under S/softmax shadow)
        const size_t kbg = (size_t)bb * 32 + sl * 8 + kt;
        s8v vf[8];
        #pragma unroll
        for (int ks = 0; ks < 2; ++ks)
            #pragma unroll
            for (int nt = 0; nt < 4; ++nt)
                vf[ks * 4 + nt] = *(const s8v*)&VF[(kbg * 8 + ks * 4 + nt) * 512 + (size_t)lane * 8];

        // ---- fixed-shift softmax: p = 2^(s*0.125/ln2 - 15/ln2), masked -> 0
        const unsigned pmh = pm >> (mt * 16);
        #pragma unroll
        for (int i = 0; i < 4; ++i) {
            float p4[4];
            #pragma unroll
            for (int nt = 0; nt < 4; ++nt) {
                float e = exp2f(fmaf(S[nt][i], 0.18033688011112042f, -21.640425613334451f));
                p4[nt] = ((pmh >> (i * 4 + nt)) & 1u) ? e : 0.f;
            }
            unsigned u0 = packTRUNC(p4[0], p4[1]);
            unsigned u1 = packTRUNC(p4[2], p4[3]);
            lro[i] += bitsf(u0 << 16) + bitsf(u0 & 0xFFFF0000u)
                    + bitsf(u1 << 16) + bitsf(u1 & 0xFFFF0000u);
            *(uint2*)&Ps[wv][quad * 4 + i][4 * c] = make_uint2(u0, u1);
        }
        pm = pmN;

        // ---- O += P V
        #pragma unroll
        for (int ks = 0; ks < 2; ++ks) {
            s8v a = *(const s8v*)&Ps[wv][c][ks * 32 + quad * 8];
            #pragma unroll
            for (int nt = 0; nt < 4; ++nt)
                O[nt] = __builtin_amdgcn_mfma_f32_16x16x32_bf16(a, vf[ks * 4 + nt], O[nt], 0, 0, 0);
        }
    }

    // ---- merge 4 slices per q-group (Obuf overlays Ps after barrier)
    __syncthreads();   // all Ps reads done
    #pragma unroll
    for (int j = 0; j < 5; ++j) {
        int idx = tid + 1024 * j;
        if (idx < 64 * 68) ((float*)Obuf)[idx] = 0.f;
    }
    __syncthreads();
    #pragma unroll
    for (int i = 0; i < 4; ++i) {
        float l = lro[i];
        l += __shfl_xor(l, 1);
        l += __shfl_xor(l, 2);
        l += __shfl_xor(l, 4);
        l += __shfl_xor(l, 8);
        if (c == 0) atomicAdd(&Lbuf[qg * 16 + quad * 4 + i], l);
        #pragma unroll
        for (int nt = 0; nt < 4; ++nt)
            atomicAdd(&Obuf[qg * 16 + quad * 4 + i][nt * 16 + c], O[nt][i]);
    }
    __syncthreads();
    {
        const int r = tid >> 4, d4 = (tid & 15) * 4;
        const float invL = 1.0f / Lbuf[r];
        float4 v = *(float4*)&Obuf[r][d4];
        float4 o = make_float4(v.x * invL, v.y * invL, v.z * invL, v.w * invL);
        *(float4*)&out[(qrow0 + r) * 64 + d4] = o;
    }
}

extern "C" void kernel_launch(void* const* d_in, const int* in_sizes, int n_in,
                              void* d_out, int out_size, void* d_ws, size_t ws_size,
                              hipStream_t stream)
{
    const float* x    = (const float*)d_in[0];
    const float* Wq   = (const float*)d_in[1];
    const float* bq   = (const float*)d_in[2];
    const float* Wk   = (const float*)d_in[3];
    const float* bk   = (const float*)d_in[4];
    const float* Wv   = (const float*)d_in[5];
    const float* bv   = (const float*)d_in[6];
    const int*   mask = (const int*)d_in[7];
    float* out = (float*)d_out;

    unsigned short* QF = (unsigned short*)d_ws;
    unsigned short* KF = QF + (size_t)16384 * 64;
    unsigned short* VF = KF + (size_t)16384 * 64;
    unsigned short* Wt = VF + (size_t)16384 * 64;
    unsigned*       PM = (unsigned*)(Wt + (size_t)192 * WID);

    prep_kernel<<<656, 256, 0, stream>>>(mask, Wq, Wk, Wv, PM, Wt);
    qkv_proj_kernel<<<1024, 256, 0, stream>>>(x, Wt, bq, bk, bv, QF, KF, VF);
    attn_kernel<<<256, 1024, 0, stream>>>(QF, KF, VF, PM, out);
}

// Round 8
// 162.941 us; speedup vs baseline: 1.3772x; 1.1543x over previous
//
#include <hip/hip_runtime.h>

typedef short  s8v   __attribute__((ext_vector_type(8)));
typedef float  f32x4 __attribute__((ext_vector_type(4)));

#define SEQ 2048
#define WID 768

__device__ __forceinline__ unsigned fbits(float f) {
    union { float f; unsigned u; } v; v.f = f; return v.u;
}
__device__ __forceinline__ float bitsf(unsigned u) {
    union { unsigned u; float f; } v; v.u = u; return v.f;
}
__device__ __forceinline__ unsigned short f2b(float f) {
    unsigned u = fbits(f);
    return (unsigned short)((u + 0x7FFFu + ((u >> 16) & 1u)) >> 16);   // RNE
}
__device__ __forceinline__ unsigned packRNE(float a, float b) {
    unsigned ta = fbits(a) + 0x7FFFu + ((fbits(a) >> 16) & 1u);
    unsigned tb = fbits(b) + 0x7FFFu + ((fbits(b) >> 16) & 1u);
    return __builtin_amdgcn_perm(tb, ta, 0x07060302u);
}
__device__ __forceinline__ unsigned packTRUNC(float a, float b) {
    return __builtin_amdgcn_perm(fbits(b), fbits(a), 0x07060302u);
}
__device__ __forceinline__ f32x4 zero4() { f32x4 z = {0.f, 0.f, 0.f, 0.f}; return z; }

// async global->LDS DMA, 16B/lane; global ptr includes lane offset, LDS base wave-uniform
__device__ __forceinline__ void async16(const unsigned short* g, unsigned short* l) {
    __builtin_amdgcn_global_load_lds(
        (const __attribute__((address_space(1))) unsigned int*)g,
        (__attribute__((address_space(3))) unsigned int*)l, 16, 0, 0);
}

// ---------------------------------------------------------------------------
// convert: pure streaming.  blocks [0,6144): x -> XF bf16 A-frag-tiled
//   XF[((rowgrp*24 + kc32)*64 + l)*8 + j] = x[rowgrp*16 + (l&15)][kc32*32 + (l>>4)*8 + j]
// blocks [6144,6656): mask -> PM (verbatim verified logic)
// blocks [6656,6728): W -> WF bf16 B-frag-tiled
//   WF[(((ntg*12 + kc)*2 + h)*64 + l)*8 + j] = W_mat[kc*64+h*32+(l>>4)*8+j][(ntg&3)*16 + (l&15)]
// ---------------------------------------------------------------------------
__global__ __launch_bounds__(256) void convert_kernel(
    const float* __restrict__ x, const int* __restrict__ mask,
    const float* __restrict__ Wq, const float* __restrict__ Wk, const float* __restrict__ Wv,
    unsigned short* __restrict__ XF, unsigned short* __restrict__ WF,
    unsigned* __restrict__ PM)
{
    const int tid = threadIdx.x;
    const int blk = blockIdx.x;
    if (blk < 6144) {
        const unsigned s = blk * 256 + tid;            // 0 .. 1,572,863
        const unsigned g = s / 1536;
        const unsigned r = s - g * 1536;
        const unsigned kc32 = r >> 6, l = r & 63;
        const unsigned row = g * 16 + (l & 15);
        const unsigned k0 = kc32 * 32 + (l >> 4) * 8;
        float4 f0 = *(const float4*)&x[(size_t)row * WID + k0];
        float4 f1 = *(const float4*)&x[(size_t)row * WID + k0 + 4];
        uint4 w;
        w.x = packRNE(f0.x, f0.y); w.y = packRNE(f0.z, f0.w);
        w.z = packRNE(f1.x, f1.y); w.w = packRNE(f1.z, f1.w);
        *(uint4*)&XF[(size_t)s * 8] = w;
    } else if (blk < 6656) {
        const int b2 = blk - 6144;
        const int gid  = b2 * 4 + (tid >> 6);          // (qb32, kb)
        const int lane = tid & 63, quad = lane >> 4, c = lane & 15;
        const int qb = gid >> 5, kb = gid & 31;
        unsigned w = 0;
        #pragma unroll
        for (int mt = 0; mt < 2; ++mt)
            #pragma unroll
            for (int i = 0; i < 4; ++i) {
                const int q = qb * 32 + mt * 16 + quad * 4 + i;
                const int4 mm = *(const int4*)&mask[(size_t)q * SEQ + kb * 64 + 4 * c];
                if (mm.x) w |= 1u << (mt * 16 + i * 4 + 0);
                if (mm.y) w |= 1u << (mt * 16 + i * 4 + 1);
                if (mm.z) w |= 1u << (mt * 16 + i * 4 + 2);
                if (mm.w) w |= 1u << (mt * 16 + i * 4 + 3);
            }
        PM[(size_t)gid * 64 + lane] = w;
    } else {
        const int s2 = (blk - 6656) * 256 + tid;       // 0 .. 18431
        const int chunk = s2 >> 6, l = s2 & 63;
        const int ntg = chunk / 24, r = chunk - ntg * 24;
        const int kc = r >> 1, h = r & 1;
        const int mat = ntg >> 2;
        const int col = (ntg & 3) * 16 + (l & 15);
        const int k0 = kc * 64 + h * 32 + (l >> 4) * 8;
        const float* Wm = (mat == 0) ? Wq : (mat == 1) ? Wk : Wv;
        float p[8];
        #pragma unroll
        for (int j = 0; j < 8; ++j) p[j] = Wm[(size_t)(k0 + j) * 64 + col];
        uint4 w;
        w.x = packRNE(p[0], p[1]); w.y = packRNE(p[2], p[3]);
        w.z = packRNE(p[4], p[5]); w.w = packRNE(p[6], p[7]);
        *(uint4*)&WF[(size_t)s2 * 8] = w;
    }
}

// ---------------------------------------------------------------------------
// proj: m97-shaped bf16 GEMM [16384x768]x[768x192].  256 blocks x 512 thr
// (8 waves, 2 blocks/CU @64KB LDS).  Block tile 64r x 192c; wave 32r x 48c
// (rg = wv>>2, cg = wv&3).  BK=64: A (8KB) + B (24KB) staged double-buffered
// via global_load_lds (fire-and-forget: no VGPR cost, compiler can't sink).
// 2-barrier K-loop; DMA for kc+1 issued after the publish barrier of kc ->
// one full compute phase of latency slack.  Zero conversion VALU in loop.
// Epilogue: verified frag-tiled QF/KF/VF writeback (block = exactly one
// 64-key tile).
// ---------------------------------------------------------------------------
__global__ __launch_bounds__(512, 4) void qkv_proj_kernel(
    const unsigned short* __restrict__ XF, const unsigned short* __restrict__ WF,
    const float* __restrict__ bq, const float* __restrict__ bk, const float* __restrict__ bv,
    unsigned short* __restrict__ QF, unsigned short* __restrict__ KF,
    unsigned short* __restrict__ VF)
{
    __shared__ unsigned short AB[2][16384];   // per buf: A shorts [0,4096), B [4096,16384)
    unsigned short (*St)[200] = (unsigned short(*)[200])AB;   // epilogue overlay (25.6KB)

    const int tid = threadIdx.x;
    const int wv = tid >> 6, lane = tid & 63, quad = lane >> 4, c = lane & 15;
    const int rg = wv >> 2, cg = wv & 3;
    const int blk = blockIdx.x;
    const int g0 = blk * 4;                    // first rowgrp of block

    float bias[3];
    #pragma unroll
    for (int nt = 0; nt < 3; ++nt) {
        int col = cg * 48 + nt * 16 + c;
        const float* B = (col < 64) ? bq : (col < 128) ? bk : bv;
        bias[nt] = B[col & 63];
    }

    // DMA issue for iter kc into buffer b: wave wv handles chunks wv*4..wv*4+3
    auto issue = [&](int kc, int b) {
        #pragma unroll
        for (int r = 0; r < 4; ++r) {
            const int d = wv * 4 + r;
            if (d < 8) {            // A chunk: rowgrp gl = d>>1, half h = d&1
                const int gl = d >> 1, h = d & 1;
                async16(XF + ((size_t)(g0 + gl) * 24 + 2 * kc + h) * 512 + lane * 8,
                        &AB[b][(gl * 2 + h) * 512]);
            } else {                // B chunk: ntg = (d-8)>>1, half h
                const int e = d - 8, ntg = e >> 1, h = e & 1;
                async16(WF + (((size_t)ntg * 12 + kc) * 2 + h) * 512 + lane * 8,
                        &AB[b][4096 + (ntg * 2 + h) * 512]);
            }
        }
    };

    f32x4 acc[2][3];
    #pragma unroll
    for (int mt = 0; mt < 2; ++mt)
        #pragma unroll
        for (int nt = 0; nt < 3; ++nt) acc[mt][nt] = zero4();

    issue(0, 0);
    for (int kc = 0; kc < 12; ++kc) {
        const int b = kc & 1;
        __syncthreads();                     // publish buf b (drain DMAs)
        if (kc < 11) issue(kc + 1, b ^ 1);   // overlapped with compute below

        s8v afr[2][2], bfr[3][2];
        #pragma unroll
        for (int mt = 0; mt < 2; ++mt)
            #pragma unroll
            for (int h = 0; h < 2; ++h)
                afr[mt][h] = *(const s8v*)&AB[b][((rg * 2 + mt) * 2 + h) * 512 + lane * 8];
        #pragma unroll
        for (int nt = 0; nt < 3; ++nt)
            #pragma unroll
            for (int h = 0; h < 2; ++h)
                bfr[nt][h] = *(const s8v*)&AB[b][4096 + ((cg * 3 + nt) * 2 + h) * 512 + lane * 8];
        #pragma unroll
        for (int h = 0; h < 2; ++h)
            #pragma unroll
            for (int mt = 0; mt < 2; ++mt)
                #pragma unroll
                for (int nt = 0; nt < 3; ++nt)
                    acc[mt][nt] = __builtin_amdgcn_mfma_f32_16x16x32_bf16(
                        afr[mt][h], bfr[nt][h], acc[mt][nt], 0, 0, 0);
        __syncthreads();                     // reads of buf b done
    }

    // ---- epilogue: bias + stage 64x192 bf16 tile (overlays AB[0])
    #pragma unroll
    for (int mt = 0; mt < 2; ++mt)
        #pragma unroll
        for (int nt = 0; nt < 3; ++nt)
            #pragma unroll
            for (int i = 0; i < 4; ++i)
                St[rg * 32 + mt * 16 + quad * 4 + i][cg * 48 + nt * 16 + c]
                    = f2b(acc[mt][nt][i] + bias[nt]);
    __syncthreads();

    {   // QF: rowgrp g = tid>>7, ks = (tid>>6)&1, frag lane l = tid&63
        const int g = tid >> 7, ks = (tid >> 6) & 1, l = tid & 63;
        uint4 v = *(uint4*)&St[g * 16 + (l & 15)][ks * 32 + (l >> 4) * 8];
        *(uint4*)&QF[(((size_t)(g0 + g)) * 2 + ks) * 512 + (size_t)l * 8] = v;
    }
    {   // KF: chunk ksnt = tid>>6 (ks = ksnt>>2, nt = ksnt&3), lane l
        const int ksnt = tid >> 6, l = tid & 63;
        const int ks = ksnt >> 2, nt = ksnt & 3;
        uint4 v = *(uint4*)&St[4 * (l & 15) + nt][64 + ks * 32 + (l >> 4) * 8];
        *(uint4*)&KF[(((size_t)blk * 8 + ksnt) * 64 + l) * 8] = v;
    }
    {   // VF: chunk ksnt, lane l: gather St columns (V transpose)
        const int ksnt = tid >> 6, l = tid & 63;
        const int ks = ksnt >> 2, nt = ksnt & 3;
        const int d = 128 + nt * 16 + (l & 15);
        const int r0 = ks * 32 + (l >> 4) * 8;
        unsigned short p[8];
        #pragma unroll
        for (int s = 0; s < 8; ++s) p[s] = St[r0 + s][d];
        uint4 w;
        w.x = (unsigned)p[0] | ((unsigned)p[1] << 16);
        w.y = (unsigned)p[2] | ((unsigned)p[3] << 16);
        w.z = (unsigned)p[4] | ((unsigned)p[5] << 16);
        w.w = (unsigned)p[6] | ((unsigned)p[7] << 16);
        *(uint4*)&VF[(((size_t)blk * 8 + ksnt) * 64 + l) * 8] = w;
    }
}

// ---------------------------------------------------------------------------
// attn: flash attention, MFMA bf16, fixed-shift softmax (identical math to
// R7, verified).  1024 thr = 4 qg x 4 sl; grid 256 (bb = blk&7 XCD swizzle).
// R8 change: V is DMA'd into LDS alongside K (single 16KB KV tile per slice,
// shared by 4 q-waves) -> V L2 traffic /4 AND no V register-loads in the
// vmcnt(0) barrier drain.  2 barriers/iter; DMA for t+1 issued at iter
// bottom.  Ps/Obuf LDS union as R7.
// ---------------------------------------------------------------------------
__global__ __launch_bounds__(1024, 4) void attn_kernel(
    const unsigned short* __restrict__ QF, const unsigned short* __restrict__ KF,
    const unsigned short* __restrict__ VF, const unsigned* __restrict__ PM,
    float* __restrict__ out)
{
    __shared__ unsigned short KV[4][8192];              // per slice: K [0,4096), V [4096,8192)
    __shared__ __align__(16) unsigned char PsOb[36864]; // Ps ∪ Obuf
    __shared__ float Lbuf[64];
    unsigned short (*Ps)[16][72] = (unsigned short(*)[16][72])PsOb;
    float (*Obuf)[68]            = (float(*)[68])PsOb;

    const int tid = threadIdx.x;
    const int wv = tid >> 6, lane = tid & 63, quad = lane >> 4, c = lane & 15;
    const int sl = wv & 3, qg = wv >> 2, mt = qg & 1;
    const int blk = blockIdx.x;
    const int bb = blk & 7, qt = blk >> 3;
    const size_t qrow0 = (size_t)bb * SEQ + qt * 64;

    if (tid < 64) Lbuf[tid] = 0.f;

    // Q frags (coalesced 1KB loads)
    s8v qf[2];
    {
        const size_t qgrp = (size_t)bb * 128 + qt * 4 + qg;
        #pragma unroll
        for (int ks = 0; ks < 2; ++ks)
            qf[ks] = *(const s8v*)&QF[(qgrp * 2 + ks) * 512 + (size_t)lane * 8];
    }

    f32x4 O[4];
    float lro[4];
    #pragma unroll
    for (int nt = 0; nt < 4; ++nt) O[nt] = zero4();
    #pragma unroll
    for (int i = 0; i < 4; ++i) lro[i] = 0.f;

    // KV DMA for tile kt of this wave's slice (16 chunks / 4 waves = 4 each)
    auto kv_dma = [&](int kt) {
        const size_t kbg = (size_t)bb * 32 + sl * 8 + kt;
        #pragma unroll
        for (int r = 0; r < 4; ++r) {
            const int d = qg * 4 + r;
            const unsigned short* src = (d < 8)
                ? KF + kbg * 4096 + (d & 7) * 512 + lane * 8
                : VF + kbg * 4096 + (d & 7) * 512 + lane * 8;
            async16(src, &KV[sl][(d >> 3) * 4096 + (d & 7) * 512]);
        }
    };

    kv_dma(0);
    for (int kt = 0; kt < 8; ++kt) {
        const unsigned pm = PM[(size_t)((qt * 2 + (qg >> 1)) * 32 + sl * 8 + kt) * 64 + lane];
        __syncthreads();   // publish KV tiles (drain DMA)

        // ---- S = Q K^T
        f32x4 S[4];
        #pragma unroll
        for (int nt = 0; nt < 4; ++nt) S[nt] = zero4();
        #pragma unroll
        for (int ks = 0; ks < 2; ++ks) {
            s8v kfr[4];
            #pragma unroll
            for (int nt = 0; nt < 4; ++nt)
                kfr[nt] = *(const s8v*)&KV[sl][((ks * 4 + nt) * 64 + lane) * 8];
            #pragma unroll
            for (int nt = 0; nt < 4; ++nt)
                S[nt] = __builtin_amdgcn_mfma_f32_16x16x32_bf16(qf[ks], kfr[nt], S[nt], 0, 0, 0);
        }

        // ---- fixed-shift softmax: p = 2^(s*0.125/ln2 - 15/ln2), masked -> 0
        const unsigned pmh = pm >> (mt * 16);
        #pragma unroll
        for (int i = 0; i < 4; ++i) {
            float p4[4];
            #pragma unroll
            for (int nt = 0; nt < 4; ++nt) {
                float e = exp2f(fmaf(S[nt][i], 0.18033688011112042f, -21.640425613334451f));
                p4[nt] = ((pmh >> (i * 4 + nt)) & 1u) ? e : 0.f;
            }
            unsigned u0 = packTRUNC(p4[0], p4[1]);
            unsigned u1 = packTRUNC(p4[2], p4[3]);
            lro[i] += bitsf(u0 << 16) + bitsf(u0 & 0xFFFF0000u)
                    + bitsf(u1 << 16) + bitsf(u1 & 0xFFFF0000u);
            *(uint2*)&Ps[wv][quad * 4 + i][4 * c] = make_uint2(u0, u1);
        }

        // ---- O += P V  (V frags from LDS)
        #pragma unroll
        for (int ks = 0; ks < 2; ++ks) {
            s8v a = *(const s8v*)&Ps[wv][c][ks * 32 + quad * 8];
            s8v vfr[4];
            #pragma unroll
            for (int nt = 0; nt < 4; ++nt)
                vfr[nt] = *(const s8v*)&KV[sl][4096 + ((ks * 4 + nt) * 64 + lane) * 8];
            #pragma unroll
            for (int nt = 0; nt < 4; ++nt)
                O[nt] = __builtin_amdgcn_mfma_f32_16x16x32_bf16(a, vfr[nt], O[nt], 0, 0, 0);
        }
        __syncthreads();   // all KV/Ps reads done
        if (kt < 7) kv_dma(kt + 1);
    }

    // ---- merge 4 slices per q-group (Obuf overlays Ps)
    #pragma unroll
    for (int j = 0; j < 5; ++j) {
        int idx = tid + 1024 * j;
        if (idx < 64 * 68) ((float*)Obuf)[idx] = 0.f;
    }
    __syncthreads();
    #pragma unroll
    for (int i = 0; i < 4; ++i) {
        float l = lro[i];
        l += __shfl_xor(l, 1);
        l += __shfl_xor(l, 2);
        l += __shfl_xor(l, 4);
        l += __shfl_xor(l, 8);
        if (c == 0) atomicAdd(&Lbuf[qg * 16 + quad * 4 + i], l);
        #pragma unroll
        for (int nt = 0; nt < 4; ++nt)
            atomicAdd(&Obuf[qg * 16 + quad * 4 + i][nt * 16 + c], O[nt][i]);
    }
    __syncthreads();
    {
        const int r = tid >> 4, d4 = (tid & 15) * 4;
        const float invL = 1.0f / Lbuf[r];
        float4 v = *(float4*)&Obuf[r][d4];
        float4 o = make_float4(v.x * invL, v.y * invL, v.z * invL, v.w * invL);
        *(float4*)&out[(qrow0 + r) * 64 + d4] = o;
    }
}

extern "C" void kernel_launch(void* const* d_in, const int* in_sizes, int n_in,
                              void* d_out, int out_size, void* d_ws, size_t ws_size,
                              hipStream_t stream)
{
    const float* x    = (const float*)d_in[0];
    const float* Wq   = (const float*)d_in[1];
    const float* bq   = (const float*)d_in[2];
    const float* Wk   = (const float*)d_in[3];
    const float* bk   = (const float*)d_in[4];
    const float* Wv   = (const float*)d_in[5];
    const float* bv   = (const float*)d_in[6];
    const int*   mask = (const int*)d_in[7];
    float* out = (float*)d_out;

    // ws: QF/KF/VF 2MB each + XF 24MB + WF 288KB + PM 512KB ≈ 31 MB
    unsigned short* QF = (unsigned short*)d_ws;
    unsigned short* KF = QF + (size_t)16384 * 64;
    unsigned short* VF = KF + (size_t)16384 * 64;
    unsigned short* XF = VF + (size_t)16384 * 64;
    unsigned short* WF = XF + (size_t)16384 * WID;
    unsigned*       PM = (unsigned*)(WF + (size_t)192 * WID);

    convert_kernel<<<6728, 256, 0, stream>>>(x, mask, Wq, Wk, Wv, XF, WF, PM);
    qkv_proj_kernel<<<256, 512, 0, stream>>>(XF, WF, bq, bk, bv, QF, KF, VF);
    attn_kernel<<<256, 1024, 0, stream>>>(QF, KF, VF, PM, out);
}